// Round 1
// baseline (83.253 us; speedup 1.0000x reference)
//
#include <hip/hip_runtime.h>

#define GAMMA 12.0f
#define DIM 256

// One 64-lane wave per triplet: lane i owns float4 chunk i (64*4 = 256 = DIM).
// Indices are < 500 for all three columns, so the gathered rows are L2-resident;
// the kernel is L2-bandwidth-bound on the gathers (~1.5 GB of cache reads).
__global__ __launch_bounds__(256) void transe_kernel(
    const float* __restrict__ node_emb,
    const float* __restrict__ rel_emb,
    const int*   __restrict__ triplets,
    float*       __restrict__ out,
    int B)
{
    const int wave = blockIdx.x * (blockDim.x >> 6) + (threadIdx.x >> 6);
    const int lane = threadIdx.x & 63;
    if (wave >= B) return;

    // Wave-uniform 12B load (broadcast from cache).
    const int h_idx = triplets[wave * 3 + 0];
    const int r_idx = triplets[wave * 3 + 1];
    const int t_idx = triplets[wave * 3 + 2];

    const float4* __restrict__ hp = (const float4*)(node_emb + (size_t)h_idx * DIM);
    const float4* __restrict__ rp = (const float4*)(rel_emb  + (size_t)r_idx * DIM);
    const float4* __restrict__ tp = (const float4*)(node_emb + (size_t)t_idx * DIM);

    const float4 h = hp[lane];
    const float4 r = rp[lane];
    const float4 t = tp[lane];

    float s = fabsf(h.x + r.x - t.x)
            + fabsf(h.y + r.y - t.y)
            + fabsf(h.z + r.z - t.z)
            + fabsf(h.w + r.w - t.w);

    // Full-wave (64-lane) reduction.
    #pragma unroll
    for (int off = 32; off > 0; off >>= 1)
        s += __shfl_down(s, off, 64);

    if (lane == 0) out[wave] = GAMMA - s;
}

extern "C" void kernel_launch(void* const* d_in, const int* in_sizes, int n_in,
                              void* d_out, int out_size, void* d_ws, size_t ws_size,
                              hipStream_t stream) {
    const float* node_emb = (const float*)d_in[0];
    const float* rel_emb  = (const float*)d_in[1];
    const int*   triplets = (const int*)d_in[2];
    float*       out      = (float*)d_out;

    const int B = out_size;                  // 500000 triplets
    const int waves_per_block = 4;           // 256 threads
    const int grid = (B + waves_per_block - 1) / waves_per_block;

    transe_kernel<<<grid, 256, 0, stream>>>(node_emb, rel_emb, triplets, out, B);
}

// Round 2
// 44.647 us; speedup vs baseline: 1.8647x; 1.8647x over previous
//
#include <hip/hip_runtime.h>

#define GAMMA 12.0f
#define DIM 256
#define NROWS 500      // rows staged for both tables; idx >= NROWS -> global fallback
#define NCHUNK 16      // DIM / CW
#define CW 16          // chunk width in halves
#define LSTRIDE 24     // LDS row stride in halves (48 B: 16B-aligned, bank-spread)

typedef _Float16 h2 __attribute__((ext_vector_type(2)));

// acc += |h + r - t| summed over one packed f16 pair, f32 accumulate via v_dot2_f32_f16
static __device__ __forceinline__ float acc_pair(unsigned uh, unsigned ur, unsigned ut, float acc) {
    h2 h = __builtin_bit_cast(h2, uh);
    h2 r = __builtin_bit_cast(h2, ur);
    h2 t = __builtin_bit_cast(h2, ut);
    h2 d = (h + r) - t;                               // v_pk_add_f16 x2
    unsigned ad = __builtin_bit_cast(unsigned, d) & 0x7FFF7FFFu;  // packed abs
    h2 one = { (_Float16)1.0f, (_Float16)1.0f };
    return __builtin_amdgcn_fdot2(__builtin_bit_cast(h2, ad), one, acc, false);
}

static __device__ __forceinline__ float acc_row16(const uint4 a, const uint4 b,
                                                  const uint4 ra, const uint4 rb,
                                                  const uint4 ta, const uint4 tb, float acc) {
    acc = acc_pair(a.x, ra.x, ta.x, acc);
    acc = acc_pair(a.y, ra.y, ta.y, acc);
    acc = acc_pair(a.z, ra.z, ta.z, acc);
    acc = acc_pair(a.w, ra.w, ta.w, acc);
    acc = acc_pair(b.x, rb.x, tb.x, acc);
    acc = acc_pair(b.y, rb.y, tb.y, acc);
    acc = acc_pair(b.z, rb.z, tb.z, acc);
    acc = acc_pair(b.w, rb.w, tb.w, acc);
    return acc;
}

// Convert first NROWS rows of node table + all NROWS rel rows to f16, chunk-major:
// out[table][chunk][row][CW]
__global__ __launch_bounds__(256) void transe_convert(
    const float* __restrict__ node, const float* __restrict__ rel,
    unsigned short* __restrict__ out)
{
    const int per = NROWS * DIM;                 // 128000
    int t = blockIdx.x * 256 + threadIdx.x;
    if (t >= 2 * per) return;
    int table = t / per;
    int e = t - table * per;                     // row*256 + d, rows < NROWS are the first floats
    int d = e & (DIM - 1);
    int row = e >> 8;
    float v = table ? rel[e] : node[e];
    int chunk = d >> 4, w = d & (CW - 1);
    _Float16 hv = (_Float16)v;
    out[table * per + chunk * (NROWS * CW) + row * CW + w] = __builtin_bit_cast(unsigned short, hv);
}

__global__ __launch_bounds__(512) void transe_main(
    const unsigned short* __restrict__ tab16,    // [2][NCHUNK][NROWS][CW] halves
    const int*   __restrict__ trip,
    const float* __restrict__ node_f32,
    const float* __restrict__ rel_f32,
    float*       __restrict__ out, int B)
{
    __shared__ __align__(16) unsigned short lnode[NROWS * LSTRIDE];  // 24 KB
    __shared__ __align__(16) unsigned short lrel [NROWS * LSTRIDE];  // 24 KB

    const int tid  = threadIdx.x;
    const int base = blockIdx.x * 1024;
    const int i0 = base + tid;
    const int i1 = base + 512 + tid;

    int h0 = 0, r0 = 0, t0 = 0, h1 = 0, r1 = 0, t1 = 0;
    const bool v0 = i0 < B, v1 = i1 < B;
    if (v0) { h0 = trip[3 * i0]; r0 = trip[3 * i0 + 1]; t0 = trip[3 * i0 + 2]; }
    if (v1) { h1 = trip[3 * i1]; r1 = trip[3 * i1 + 1]; t1 = trip[3 * i1 + 2]; }
    const bool l0 = v0 && h0 < NROWS && t0 < NROWS && r0 < NROWS;
    const bool l1 = v1 && h1 < NROWS && t1 < NROWS && r1 < NROWS;

    float acc0 = 0.f, acc1 = 0.f;

    const uint4* gnode = (const uint4*)tab16;
    const uint4* grel  = (const uint4*)(tab16 + NCHUNK * NROWS * CW);
    const int segs = NROWS * CW / 8;             // 16B segments per chunk blob = 1000

    for (int c = 0; c < NCHUNK; ++c) {
        const uint4* gn = gnode + c * segs;
        const uint4* gr = grel  + c * segs;
        // stage both tables' chunk c into LDS (reg-staged, padded rows)
        for (int s = tid; s < segs; s += 512) {
            uint4 x = gn[s];
            int row = s >> 1, part = s & 1;
            *(uint4*)&lnode[row * LSTRIDE + part * 8] = x;
        }
        for (int s = tid; s < segs; s += 512) {
            uint4 x = gr[s];
            int row = s >> 1, part = s & 1;
            *(uint4*)&lrel[row * LSTRIDE + part * 8] = x;
        }
        __syncthreads();

        if (l0) {
            const uint4* hp = (const uint4*)&lnode[h0 * LSTRIDE];
            const uint4* rp = (const uint4*)&lrel [r0 * LSTRIDE];
            const uint4* tp = (const uint4*)&lnode[t0 * LSTRIDE];
            acc0 = acc_row16(hp[0], hp[1], rp[0], rp[1], tp[0], tp[1], acc0);
        }
        if (l1) {
            const uint4* hp = (const uint4*)&lnode[h1 * LSTRIDE];
            const uint4* rp = (const uint4*)&lrel [r1 * LSTRIDE];
            const uint4* tp = (const uint4*)&lnode[t1 * LSTRIDE];
            acc1 = acc_row16(hp[0], hp[1], rp[0], rp[1], tp[0], tp[1], acc1);
        }
        __syncthreads();
    }

    if (v0) {
        if (l0) out[i0] = GAMMA - acc0;
        else {
            float a = 0.f;
            for (int d = 0; d < DIM; ++d)
                a += fabsf(node_f32[(size_t)h0 * DIM + d] + rel_f32[(size_t)r0 * DIM + d]
                         - node_f32[(size_t)t0 * DIM + d]);
            out[i0] = GAMMA - a;
        }
    }
    if (v1) {
        if (l1) out[i1] = GAMMA - acc1;
        else {
            float a = 0.f;
            for (int d = 0; d < DIM; ++d)
                a += fabsf(node_f32[(size_t)h1 * DIM + d] + rel_f32[(size_t)r1 * DIM + d]
                         - node_f32[(size_t)t1 * DIM + d]);
            out[i1] = GAMMA - a;
        }
    }
}

// Round-1 fallback (used only if d_ws is too small for the f16 tables)
__global__ __launch_bounds__(256) void transe_direct(
    const float* __restrict__ node_emb,
    const float* __restrict__ rel_emb,
    const int*   __restrict__ triplets,
    float*       __restrict__ out, int B)
{
    const int wave = blockIdx.x * (blockDim.x >> 6) + (threadIdx.x >> 6);
    const int lane = threadIdx.x & 63;
    if (wave >= B) return;
    const int h_idx = triplets[wave * 3 + 0];
    const int r_idx = triplets[wave * 3 + 1];
    const int t_idx = triplets[wave * 3 + 2];
    const float4 h = ((const float4*)(node_emb + (size_t)h_idx * DIM))[lane];
    const float4 r = ((const float4*)(rel_emb  + (size_t)r_idx * DIM))[lane];
    const float4 t = ((const float4*)(node_emb + (size_t)t_idx * DIM))[lane];
    float s = fabsf(h.x + r.x - t.x) + fabsf(h.y + r.y - t.y)
            + fabsf(h.z + r.z - t.z) + fabsf(h.w + r.w - t.w);
    #pragma unroll
    for (int off = 32; off > 0; off >>= 1) s += __shfl_down(s, off, 64);
    if (lane == 0) out[wave] = GAMMA - s;
}

extern "C" void kernel_launch(void* const* d_in, const int* in_sizes, int n_in,
                              void* d_out, int out_size, void* d_ws, size_t ws_size,
                              hipStream_t stream) {
    const float* node_emb = (const float*)d_in[0];
    const float* rel_emb  = (const float*)d_in[1];
    const int*   triplets = (const int*)d_in[2];
    float*       out      = (float*)d_out;
    const int B = out_size;

    const size_t ws_needed = (size_t)2 * NROWS * DIM * sizeof(unsigned short); // 512 KB
    if (ws_size < ws_needed) {
        const int grid = (B + 3) / 4;
        transe_direct<<<grid, 256, 0, stream>>>(node_emb, rel_emb, triplets, out, B);
        return;
    }

    unsigned short* tab16 = (unsigned short*)d_ws;

    const int conv_elems = 2 * NROWS * DIM;
    transe_convert<<<(conv_elems + 255) / 256, 256, 0, stream>>>(node_emb, rel_emb, tab16);

    const int grid = (B + 1023) / 1024;   // 1024 triplets per block, 2 per thread
    transe_main<<<grid, 512, 0, stream>>>(tab16, triplets, node_emb, rel_emb, out, B);
}

// Round 3
// 40.279 us; speedup vs baseline: 2.0669x; 1.1084x over previous
//
#include <hip/hip_runtime.h>

#define GAMMA 12.0f
#define DIM 256
#define NROWS 500
#define CW 64                               // halves per chunk slice (128 B rows)
#define NCHUNK 4                            // DIM / CW
#define ROWS_PAD 504                        // padded rows: region = 504*128 B = 63 KiB = 63*1024
#define REGION_HALVES (ROWS_PAD * CW)       // 32256 halves = 64512 B
#define THREADS 1024
#define WAVES 16
#define PASSES 16
#define TPB (WAVES * 8 * PASSES)            // 2048 triplets per block

typedef _Float16 h2 __attribute__((ext_vector_type(2)));

// acc += |h + r - t| over one packed f16 pair, f32 accumulate via v_dot2_f32_f16
static __device__ __forceinline__ float acc_pair(unsigned uh, unsigned ur, unsigned ut, float acc) {
    h2 h = __builtin_bit_cast(h2, uh);
    h2 r = __builtin_bit_cast(h2, ur);
    h2 t = __builtin_bit_cast(h2, ut);
    h2 d = (h + r) - t;                                           // v_pk_add_f16 x2
    unsigned ad = __builtin_bit_cast(unsigned, d) & 0x7FFF7FFFu;  // packed abs
    h2 one = { (_Float16)1.0f, (_Float16)1.0f };
    return __builtin_amdgcn_fdot2(__builtin_bit_cast(h2, ad), one, acc, false);
}

// tab16 layout: [table][chunk][ROWS_PAD][CW] halves (rows >= NROWS are junk, never read)
__global__ __launch_bounds__(256) void transe_convert(
    const float* __restrict__ node, const float* __restrict__ rel,
    unsigned short* __restrict__ out)
{
    const int per = NROWS * DIM;
    int t = blockIdx.x * 256 + threadIdx.x;
    if (t >= 2 * per) return;
    int table = t / per;
    int e = t - table * per;
    int row = e >> 8;
    int d = e & (DIM - 1);
    float v = table ? rel[e] : node[e];
    int c = d >> 6, w = d & (CW - 1);
    _Float16 hv = (_Float16)v;
    out[(size_t)(table * NCHUNK + c) * REGION_HALVES + row * CW + w] =
        __builtin_bit_cast(unsigned short, hv);
}

// 8 lanes per triplet; per chunk each lane reads 16 B of each of h/r/t rows.
// Wave-level ds_read_b128 = 8 rows x 128 consecutive B -> every bank hit exactly
// 8x -> zero bank conflicts regardless of row randomness.
__global__ __launch_bounds__(THREADS) void transe_main(
    const unsigned short* __restrict__ tab16,
    const int* __restrict__ trip,
    const float* __restrict__ node_f32,
    const float* __restrict__ rel_f32,
    float* __restrict__ out, int B)
{
    __shared__ __align__(16) unsigned short ltab[2 * REGION_HALVES]; // 129024 B
    __shared__ __align__(16) int ltrip[TPB * 4];                     // 32768 B

    const int tid  = threadIdx.x;
    const int wid  = tid >> 6;
    const int lane = tid & 63;
    const int g    = lane >> 3;  // group (triplet) within wave
    const int m    = lane & 7;   // member within group

    const long base = (long)blockIdx.x * TPB;

    // stage this block's triplets as int4 (one b128 broadcast per pass later)
    for (int s = tid; s < TPB; s += THREADS) {
        long j = base + s;
        int h = 0, r = 0, t = 0;
        if (j < B) { h = trip[3 * j]; r = trip[3 * j + 1]; t = trip[3 * j + 2]; }
        *(int4*)&ltrip[4 * s] = make_int4(h, r, t, 0);
    }

    float acc[PASSES];
    #pragma unroll
    for (int p = 0; p < PASSES; ++p) acc[p] = 0.f;

    for (int c = 0; c < NCHUNK; ++c) {
        __syncthreads();  // previous chunk's reads done (no-op cost at c=0; also fences ltrip)
        // stage both tables' chunk c: 126 wave-iters x 1024 B, linear copy
        for (int i = wid; i < 126; i += WAVES) {
            int region = (i >= 63) ? 1 : 0;
            int k = i - region * 63;
            const uint4* src = (const uint4*)(tab16 + (size_t)(region * NCHUNK + c) * REGION_HALVES)
                               + (size_t)k * 64 + lane;
            uint4 x = *src;
            *((uint4*)&ltab[region * REGION_HALVES] + k * 64 + lane) = x;
        }
        __syncthreads();

        #pragma unroll
        for (int p = 0; p < PASSES; ++p) {
            int slot = wid * (8 * PASSES) + p * 8 + g;
            int4 iv = *(const int4*)&ltrip[4 * slot];     // 8-lane broadcast
            int hi = min(iv.x, NROWS - 1);
            int ri = min(iv.y, NROWS - 1);
            int ti = min(iv.z, NROWS - 1);
            const uint4 hv = *(const uint4*)&ltab[hi * CW + m * 8];
            const uint4 rv = *(const uint4*)&ltab[REGION_HALVES + ri * CW + m * 8];
            const uint4 tv = *(const uint4*)&ltab[ti * CW + m * 8];
            float a = acc[p];
            a = acc_pair(hv.x, rv.x, tv.x, a);
            a = acc_pair(hv.y, rv.y, tv.y, a);
            a = acc_pair(hv.z, rv.z, tv.z, a);
            a = acc_pair(hv.w, rv.w, tv.w, a);
            acc[p] = a;
        }
    }

    // reduce over the 8 members of each group, member 0 writes
    #pragma unroll
    for (int p = 0; p < PASSES; ++p) {
        float a = acc[p];
        a += __shfl_xor(a, 1, 64);
        a += __shfl_xor(a, 2, 64);
        a += __shfl_xor(a, 4, 64);
        if (m == 0) {
            int slot = wid * (8 * PASSES) + p * 8 + g;
            long j = base + slot;
            if (j < B) {
                int4 iv = *(const int4*)&ltrip[4 * slot];
                if (iv.x < NROWS && iv.y < NROWS && iv.z < NROWS) {
                    out[j] = GAMMA - a;
                } else {  // paranoia fallback (indices are < 500 for this generator)
                    float s = 0.f;
                    for (int d = 0; d < DIM; ++d)
                        s += fabsf(node_f32[(size_t)iv.x * DIM + d] + rel_f32[(size_t)iv.y * DIM + d]
                                 - node_f32[(size_t)iv.z * DIM + d]);
                    out[j] = GAMMA - s;
                }
            }
        }
    }
}

// Round-1 fallback (only if d_ws is too small for the f16 tables)
__global__ __launch_bounds__(256) void transe_direct(
    const float* __restrict__ node_emb,
    const float* __restrict__ rel_emb,
    const int*   __restrict__ triplets,
    float*       __restrict__ out, int B)
{
    const int wave = blockIdx.x * (blockDim.x >> 6) + (threadIdx.x >> 6);
    const int lane = threadIdx.x & 63;
    if (wave >= B) return;
    const int h_idx = triplets[wave * 3 + 0];
    const int r_idx = triplets[wave * 3 + 1];
    const int t_idx = triplets[wave * 3 + 2];
    const float4 h = ((const float4*)(node_emb + (size_t)h_idx * DIM))[lane];
    const float4 r = ((const float4*)(rel_emb  + (size_t)r_idx * DIM))[lane];
    const float4 t = ((const float4*)(node_emb + (size_t)t_idx * DIM))[lane];
    float s = fabsf(h.x + r.x - t.x) + fabsf(h.y + r.y - t.y)
            + fabsf(h.z + r.z - t.z) + fabsf(h.w + r.w - t.w);
    #pragma unroll
    for (int off = 32; off > 0; off >>= 1) s += __shfl_down(s, off, 64);
    if (lane == 0) out[wave] = GAMMA - s;
}

extern "C" void kernel_launch(void* const* d_in, const int* in_sizes, int n_in,
                              void* d_out, int out_size, void* d_ws, size_t ws_size,
                              hipStream_t stream) {
    const float* node_emb = (const float*)d_in[0];
    const float* rel_emb  = (const float*)d_in[1];
    const int*   triplets = (const int*)d_in[2];
    float*       out      = (float*)d_out;
    const int B = out_size;

    const size_t ws_needed = (size_t)2 * NCHUNK * REGION_HALVES * sizeof(unsigned short); // 516096
    if (ws_size < ws_needed) {
        const int grid = (B + 3) / 4;
        transe_direct<<<grid, 256, 0, stream>>>(node_emb, rel_emb, triplets, out, B);
        return;
    }

    unsigned short* tab16 = (unsigned short*)d_ws;

    const int conv_elems = 2 * NROWS * DIM;
    transe_convert<<<(conv_elems + 255) / 256, 256, 0, stream>>>(node_emb, rel_emb, tab16);

    const int grid = (B + TPB - 1) / TPB;   // 245 blocks, one dispatch round
    transe_main<<<grid, THREADS, 0, stream>>>(tab16, triplets, node_emb, rel_emb, out, B);
}

// Round 4
// 30.813 us; speedup vs baseline: 2.7019x; 1.3072x over previous
//
#include <hip/hip_runtime.h>

#define GAMMA 12.0f
#define DIM 256
#define NROWS 500
#define CW 64                               // halves per chunk slice (128 B rows)
#define NCHUNK 4                            // DIM / CW
#define ROWS_PAD 504                        // region = 504*128 B = 64512 B = 63 KiB
#define REGION_HALVES (ROWS_PAD * CW)       // 32256
#define REGION_BYTES (REGION_HALVES * 2)    // 64512
#define THREADS 1024
#define WAVES 16
#define PASSES 16
#define TPB 2048                            // triplets per block

typedef _Float16 h2 __attribute__((ext_vector_type(2)));

static __device__ __forceinline__ unsigned short f2h(float x) {
    _Float16 h = (_Float16)x;
    return __builtin_bit_cast(unsigned short, h);
}

// acc += |h + r - t| over one packed f16 pair, f32 accumulate via v_dot2_f32_f16
static __device__ __forceinline__ float acc_pair(unsigned uh, unsigned ur, unsigned ut, float acc) {
    h2 h = __builtin_bit_cast(h2, uh);
    h2 r = __builtin_bit_cast(h2, ur);
    h2 t = __builtin_bit_cast(h2, ut);
    h2 d = (h + r) - t;                                           // v_pk_add_f16 x2
    unsigned ad = __builtin_bit_cast(unsigned, d) & 0x7FFF7FFFu;  // packed abs
    h2 one = { (_Float16)1.0f, (_Float16)1.0f };
    return __builtin_amdgcn_fdot2(__builtin_bit_cast(h2, ad), one, acc, false);
}

// tab16 layout: [table][chunk][ROWS_PAD][CW] halves (rows >= NROWS junk, never read)
// 8 elements per thread, uint4 stores.
__global__ __launch_bounds__(256) void transe_convert(
    const float* __restrict__ node, const float* __restrict__ rel,
    unsigned short* __restrict__ out)
{
    const int per = NROWS * DIM;                 // 128000
    int t8 = (blockIdx.x * 256 + threadIdx.x) * 8;
    if (t8 >= 2 * per) return;
    int table = t8 >= per;
    int e = t8 - table * per;
    const float* src = table ? rel : node;
    float4 f0 = *(const float4*)(src + e);
    float4 f1 = *(const float4*)(src + e + 4);
    int row = e >> 8;
    int d = e & (DIM - 1);
    int c = d >> 6, w = d & (CW - 1);            // w multiple of 8 -> 16B aligned store
    union { unsigned short us[8]; uint4 v; } o;
    o.us[0] = f2h(f0.x); o.us[1] = f2h(f0.y); o.us[2] = f2h(f0.z); o.us[3] = f2h(f0.w);
    o.us[4] = f2h(f1.x); o.us[5] = f2h(f1.y); o.us[6] = f2h(f1.z); o.us[7] = f2h(f1.w);
    *(uint4*)(out + (size_t)(table * NCHUNK + c) * REGION_HALVES + row * CW + w) = o.v;
}

// 8 lanes per triplet; per chunk each lane reads 16 B of each of h/r/t 128 B rows.
// Wave ds_read_b128 = 8 rows x 128 consecutive B -> every bank hit exactly 8x ->
// zero conflicts regardless of row randomness. Triplet indices packed in VGPRs.
__global__ __launch_bounds__(THREADS) void transe_main(
    const unsigned short* __restrict__ tab16,
    const int* __restrict__ trip,
    const float* __restrict__ node_f32,
    const float* __restrict__ rel_f32,
    float* __restrict__ out, int B)
{
    __shared__ __align__(16) unsigned short ltab[2 * REGION_HALVES]; // 129024 B
    __shared__ int ltrip[TPB];                                       // 8192 B packed

    const int tid  = threadIdx.x;
    const int wid  = tid >> 6;
    const int lane = tid & 63;
    const int g    = lane >> 3;   // group (triplet) within wave
    const int m    = lane & 7;    // member within group
    const int moff = m * 16;
    const long base = (long)blockIdx.x * TPB;

    const char* srcb = (const char*)tab16;
    char* ldsb = (char*)ltab;

    // ---- issue chunk-0 staging (async global->LDS, wave-uniform dest + lane*16) ----
    #pragma unroll 1
    for (int i = wid; i < 126; i += WAVES) {
        int region = i >= 63;
        int k = region ? (i - 63) : i;
        const char* src = srcb + (size_t)(region * NCHUNK + 0) * REGION_BYTES
                        + (size_t)k * 1024 + (size_t)lane * 16;
        char* dst = ldsb + region * REGION_BYTES + k * 1024;
        __builtin_amdgcn_global_load_lds(
            (const __attribute__((address_space(1))) unsigned int*)src,
            (__attribute__((address_space(3))) unsigned int*)dst, 16, 0, 0);
    }

    // ---- pack triplets: h | r<<10 | t<<20 | oob<<30 | invalid<<31 (clamped) ----
    for (int s = tid; s < TPB; s += THREADS) {
        long j = base + s;
        unsigned pk;
        if (j < B) {
            int h = trip[3 * j], r = trip[3 * j + 1], t = trip[3 * j + 2];
            unsigned oob = ((unsigned)h >= NROWS || (unsigned)r >= NROWS || (unsigned)t >= NROWS)
                           ? (1u << 30) : 0u;
            unsigned hc = (unsigned)min(max(h, 0), NROWS - 1);
            unsigned rc = (unsigned)min(max(r, 0), NROWS - 1);
            unsigned tc = (unsigned)min(max(t, 0), NROWS - 1);
            pk = hc | (rc << 10) | (tc << 20) | oob;
        } else pk = 1u << 31;
        ltrip[s] = (int)pk;
    }
    __syncthreads();   // ltrip ready AND chunk-0 staged (implicit vmcnt/lgkm drain)

    // my 16 packed indices -> registers (b32 broadcast reads, conflict-free)
    unsigned pidx[PASSES];
    #pragma unroll
    for (int p = 0; p < PASSES; ++p)
        pidx[p] = (unsigned)ltrip[wid * (8 * PASSES) + p * 8 + g];

    float acc[PASSES];
    #pragma unroll
    for (int p = 0; p < PASSES; ++p) acc[p] = 0.f;

    for (int c = 0; c < NCHUNK; ++c) {
        if (c) {
            __syncthreads();   // all reads of previous chunk done
            #pragma unroll 1
            for (int i = wid; i < 126; i += WAVES) {
                int region = i >= 63;
                int k = region ? (i - 63) : i;
                const char* src = srcb + (size_t)(region * NCHUNK + c) * REGION_BYTES
                                + (size_t)k * 1024 + (size_t)lane * 16;
                char* dst = ldsb + region * REGION_BYTES + k * 1024;
                __builtin_amdgcn_global_load_lds(
                    (const __attribute__((address_space(1))) unsigned int*)src,
                    (__attribute__((address_space(3))) unsigned int*)dst, 16, 0, 0);
            }
            __syncthreads();   // chunk c staged
        }

        #pragma unroll
        for (int p = 0; p < PASSES; ++p) {
            unsigned pk = pidx[p];
            unsigned hb = (pk & 1023u) << 7;
            unsigned rb = ((pk >> 10) & 1023u) << 7;
            unsigned tb = ((pk >> 20) & 1023u) << 7;
            uint4 hv = *(const uint4*)(ldsb + hb + moff);
            uint4 rv = *(const uint4*)(ldsb + REGION_BYTES + rb + moff);
            uint4 tv = *(const uint4*)(ldsb + tb + moff);
            float a = acc[p];
            a = acc_pair(hv.x, rv.x, tv.x, a);
            a = acc_pair(hv.y, rv.y, tv.y, a);
            a = acc_pair(hv.z, rv.z, tv.z, a);
            a = acc_pair(hv.w, rv.w, tv.w, a);
            acc[p] = a;
        }
    }

    // reduce over the 8 members of each group; member 0 writes
    #pragma unroll
    for (int p = 0; p < PASSES; ++p) {
        float a = acc[p];
        a += __shfl_xor(a, 1, 64);
        a += __shfl_xor(a, 2, 64);
        a += __shfl_xor(a, 4, 64);
        if (m == 0) {
            unsigned pk = pidx[p];
            int slot = wid * (8 * PASSES) + p * 8 + g;
            long j = base + slot;
            if (!(pk >> 30)) {
                out[j] = GAMMA - a;
            } else if (!(pk >> 31)) {   // oob index: exact f32 fallback (never hit here)
                int hh = trip[3 * j], rr = trip[3 * j + 1], tt = trip[3 * j + 2];
                float s = 0.f;
                for (int d = 0; d < DIM; ++d)
                    s += fabsf(node_f32[(size_t)hh * DIM + d] + rel_f32[(size_t)rr * DIM + d]
                             - node_f32[(size_t)tt * DIM + d]);
                out[j] = GAMMA - s;
            }
        }
    }
}

// Round-1 fallback (only if d_ws is too small for the f16 tables)
__global__ __launch_bounds__(256) void transe_direct(
    const float* __restrict__ node_emb,
    const float* __restrict__ rel_emb,
    const int*   __restrict__ triplets,
    float*       __restrict__ out, int B)
{
    const int wave = blockIdx.x * (blockDim.x >> 6) + (threadIdx.x >> 6);
    const int lane = threadIdx.x & 63;
    if (wave >= B) return;
    const int h_idx = triplets[wave * 3 + 0];
    const int r_idx = triplets[wave * 3 + 1];
    const int t_idx = triplets[wave * 3 + 2];
    const float4 h = ((const float4*)(node_emb + (size_t)h_idx * DIM))[lane];
    const float4 r = ((const float4*)(rel_emb  + (size_t)r_idx * DIM))[lane];
    const float4 t = ((const float4*)(node_emb + (size_t)t_idx * DIM))[lane];
    float s = fabsf(h.x + r.x - t.x) + fabsf(h.y + r.y - t.y)
            + fabsf(h.z + r.z - t.z) + fabsf(h.w + r.w - t.w);
    #pragma unroll
    for (int off = 32; off > 0; off >>= 1) s += __shfl_down(s, off, 64);
    if (lane == 0) out[wave] = GAMMA - s;
}

extern "C" void kernel_launch(void* const* d_in, const int* in_sizes, int n_in,
                              void* d_out, int out_size, void* d_ws, size_t ws_size,
                              hipStream_t stream) {
    const float* node_emb = (const float*)d_in[0];
    const float* rel_emb  = (const float*)d_in[1];
    const int*   triplets = (const int*)d_in[2];
    float*       out      = (float*)d_out;
    const int B = out_size;

    const size_t ws_needed = (size_t)2 * NCHUNK * REGION_HALVES * sizeof(unsigned short); // 516096
    if (ws_size < ws_needed) {
        const int grid = (B + 3) / 4;
        transe_direct<<<grid, 256, 0, stream>>>(node_emb, rel_emb, triplets, out, B);
        return;
    }

    unsigned short* tab16 = (unsigned short*)d_ws;

    const int conv_threads = 2 * NROWS * DIM / 8;   // 32000
    transe_convert<<<(conv_threads + 255) / 256, 256, 0, stream>>>(node_emb, rel_emb, tab16);

    const int grid = (B + TPB - 1) / TPB;           // 245 blocks, 1/CU
    transe_main<<<grid, THREADS, 0, stream>>>(tab16, triplets, node_emb, rel_emb, out, B);
}

// Round 5
// 28.688 us; speedup vs baseline: 2.9020x; 1.0741x over previous
//
#include <hip/hip_runtime.h>

#define GAMMA 12.0f
#define DIM 256
#define NROWS 500
#define CW 64                               // halves per chunk slice (128 B rows)
#define NCHUNK 4                            // DIM / CW
#define ROWS_PAD 504                        // region = 504*128 B = 64512 B
#define REGION_HALVES (ROWS_PAD * CW)       // 32256
#define REGION_BYTES (REGION_HALVES * 2)    // 64512
#define STAGE_ITERS (REGION_BYTES / 1024)   // 63 wave-loads of 1024 B per chunk
#define THREADS 1024
#define WAVES 16
#define PASSES 16
#define TPB 2048                            // triplets per block

typedef _Float16 h2 __attribute__((ext_vector_type(2)));

static __device__ __forceinline__ unsigned short f2h(float x) {
    _Float16 h = (_Float16)x;
    return __builtin_bit_cast(unsigned short, h);
}

// acc += |h + r - t| over one packed f16 pair, f32 accumulate via v_dot2_f32_f16
static __device__ __forceinline__ float acc_pair(unsigned uh, unsigned ur, unsigned ut, float acc) {
    h2 h = __builtin_bit_cast(h2, uh);
    h2 r = __builtin_bit_cast(h2, ur);
    h2 t = __builtin_bit_cast(h2, ut);
    h2 d = (h + r) - t;                                           // v_pk_add_f16 x2
    unsigned ad = __builtin_bit_cast(unsigned, d) & 0x7FFF7FFFu;  // packed abs
    h2 one = { (_Float16)1.0f, (_Float16)1.0f };
    return __builtin_amdgcn_fdot2(__builtin_bit_cast(h2, ad), one, acc, false);
}

// tab16 layout: [table][chunk][ROWS_PAD][CW] halves (rows >= NROWS junk, never read)
__global__ __launch_bounds__(256) void transe_convert(
    const float* __restrict__ node, const float* __restrict__ rel,
    unsigned short* __restrict__ out)
{
    const int per = NROWS * DIM;                 // 128000
    int t8 = (blockIdx.x * 256 + threadIdx.x) * 8;
    if (t8 >= 2 * per) return;
    int table = t8 >= per;
    int e = t8 - table * per;
    const float* src = table ? rel : node;
    float4 f0 = *(const float4*)(src + e);
    float4 f1 = *(const float4*)(src + e + 4);
    int row = e >> 8;
    int d = e & (DIM - 1);
    int c = d >> 6, w = d & (CW - 1);            // w multiple of 8 -> 16B aligned store
    union { unsigned short us[8]; uint4 v; } o;
    o.us[0] = f2h(f0.x); o.us[1] = f2h(f0.y); o.us[2] = f2h(f0.z); o.us[3] = f2h(f0.w);
    o.us[4] = f2h(f1.x); o.us[5] = f2h(f1.y); o.us[6] = f2h(f1.z); o.us[7] = f2h(f1.w);
    *(uint4*)(out + (size_t)(table * NCHUNK + c) * REGION_HALVES + row * CW + w) = o.v;
}

// 8 lanes per triplet, 128 B per row-chunk. h,t come from a double-buffered node
// region in LDS (wave ds_read_b128 = 8 rows x 128 B -> every bank hit exactly 8x,
// zero conflicts). r comes straight from the L2-resident global f16 table on the
// VMEM pipe (coalesced 128 B segments), overlapping the LDS port. Next node chunk
// is staged via global_load_lds into the other buffer while computing.
__global__ __launch_bounds__(THREADS) void transe_main(
    const unsigned short* __restrict__ tab16,
    const int* __restrict__ trip,
    const float* __restrict__ node_f32,
    const float* __restrict__ rel_f32,
    float* __restrict__ out, int B)
{
    __shared__ __align__(16) unsigned short lbuf[2 * REGION_HALVES]; // 129024 B
    __shared__ int ltrip[TPB];                                       // 8192 B packed

    const int tid  = threadIdx.x;
    const int wid  = tid >> 6;
    const int lane = tid & 63;
    const int g    = lane >> 3;   // group (triplet) within wave
    const int m    = lane & 7;    // member within group
    const int moff = m * 16;
    const long base = (long)blockIdx.x * TPB;

    const char* srcb = (const char*)tab16;
    char* ldsb = (char*)lbuf;

    // ---- issue chunk-0 node staging into buf0 (async global->LDS) ----
    #pragma unroll 1
    for (int i = wid; i < STAGE_ITERS; i += WAVES) {
        const char* src = srcb + (size_t)i * 1024 + (size_t)lane * 16;
        char* dst = ldsb + i * 1024;
        __builtin_amdgcn_global_load_lds(
            (const __attribute__((address_space(1))) unsigned int*)src,
            (__attribute__((address_space(3))) unsigned int*)dst, 16, 0, 0);
    }

    // ---- pack triplets: h | r<<10 | t<<20 | oob<<30 | invalid<<31 (clamped) ----
    for (int s = tid; s < TPB; s += THREADS) {
        long j = base + s;
        unsigned pk;
        if (j < B) {
            int h = trip[3 * j], r = trip[3 * j + 1], t = trip[3 * j + 2];
            unsigned oob = ((unsigned)h >= NROWS || (unsigned)r >= NROWS || (unsigned)t >= NROWS)
                           ? (1u << 30) : 0u;
            unsigned hc = (unsigned)min(max(h, 0), NROWS - 1);
            unsigned rc = (unsigned)min(max(r, 0), NROWS - 1);
            unsigned tc = (unsigned)min(max(t, 0), NROWS - 1);
            pk = hc | (rc << 10) | (tc << 20) | oob;
        } else pk = 1u << 31;
        ltrip[s] = (int)pk;
    }
    __syncthreads();   // ltrip ready AND chunk-0 staged

    unsigned pidx[PASSES];
    #pragma unroll
    for (int p = 0; p < PASSES; ++p)
        pidx[p] = (unsigned)ltrip[wid * (8 * PASSES) + p * 8 + g];

    float acc[PASSES];
    #pragma unroll
    for (int p = 0; p < PASSES; ++p) acc[p] = 0.f;

    for (int c = 0; c < NCHUNK; ++c) {
        // stage next node chunk into the other buffer (flies during compute)
        if (c + 1 < NCHUNK) {
            const char* cb = srcb + (size_t)(c + 1) * REGION_BYTES;
            char* db = ldsb + ((c + 1) & 1) * REGION_BYTES;
            #pragma unroll 1
            for (int i = wid; i < STAGE_ITERS; i += WAVES) {
                __builtin_amdgcn_global_load_lds(
                    (const __attribute__((address_space(1))) unsigned int*)
                        (cb + (size_t)i * 1024 + (size_t)lane * 16),
                    (__attribute__((address_space(3))) unsigned int*)(db + i * 1024),
                    16, 0, 0);
            }
        }

        const char* lbase = ldsb + (c & 1) * REGION_BYTES;
        const char* relc  = srcb + (size_t)(NCHUNK + c) * REGION_BYTES;

        uint4 rnext = *(const uint4*)(relc + (((pidx[0] >> 10) & 1023u) << 7) + moff);
        #pragma unroll
        for (int p = 0; p < PASSES; ++p) {
            uint4 rv = rnext;
            if (p + 1 < PASSES)
                rnext = *(const uint4*)(relc + (((pidx[p + 1] >> 10) & 1023u) << 7) + moff);
            unsigned pk = pidx[p];
            uint4 hv = *(const uint4*)(lbase + ((pk & 1023u) << 7) + moff);
            uint4 tv = *(const uint4*)(lbase + (((pk >> 20) & 1023u) << 7) + moff);
            float a = acc[p];
            a = acc_pair(hv.x, rv.x, tv.x, a);
            a = acc_pair(hv.y, rv.y, tv.y, a);
            a = acc_pair(hv.z, rv.z, tv.z, a);
            a = acc_pair(hv.w, rv.w, tv.w, a);
            acc[p] = a;
        }

        __syncthreads();  // all waves done reading buf[c&1]; stage(c+1) drained pre-barrier
    }

    // reduce over the 8 members of each group; member 0 writes
    #pragma unroll
    for (int p = 0; p < PASSES; ++p) {
        float a = acc[p];
        a += __shfl_xor(a, 1, 64);
        a += __shfl_xor(a, 2, 64);
        a += __shfl_xor(a, 4, 64);
        if (m == 0) {
            unsigned pk = pidx[p];
            int slot = wid * (8 * PASSES) + p * 8 + g;
            long j = base + slot;
            if (!(pk >> 30)) {
                out[j] = GAMMA - a;
            } else if (!(pk >> 31)) {   // oob index: exact f32 fallback (never hit here)
                int hh = trip[3 * j], rr = trip[3 * j + 1], tt = trip[3 * j + 2];
                float s = 0.f;
                for (int d = 0; d < DIM; ++d)
                    s += fabsf(node_f32[(size_t)hh * DIM + d] + rel_f32[(size_t)rr * DIM + d]
                             - node_f32[(size_t)tt * DIM + d]);
                out[j] = GAMMA - s;
            }
        }
    }
}

// Round-1 fallback (only if d_ws is too small for the f16 tables)
__global__ __launch_bounds__(256) void transe_direct(
    const float* __restrict__ node_emb,
    const float* __restrict__ rel_emb,
    const int*   __restrict__ triplets,
    float*       __restrict__ out, int B)
{
    const int wave = blockIdx.x * (blockDim.x >> 6) + (threadIdx.x >> 6);
    const int lane = threadIdx.x & 63;
    if (wave >= B) return;
    const int h_idx = triplets[wave * 3 + 0];
    const int r_idx = triplets[wave * 3 + 1];
    const int t_idx = triplets[wave * 3 + 2];
    const float4 h = ((const float4*)(node_emb + (size_t)h_idx * DIM))[lane];
    const float4 r = ((const float4*)(rel_emb  + (size_t)r_idx * DIM))[lane];
    const float4 t = ((const float4*)(node_emb + (size_t)t_idx * DIM))[lane];
    float s = fabsf(h.x + r.x - t.x) + fabsf(h.y + r.y - t.y)
            + fabsf(h.z + r.z - t.z) + fabsf(h.w + r.w - t.w);
    #pragma unroll
    for (int off = 32; off > 0; off >>= 1) s += __shfl_down(s, off, 64);
    if (lane == 0) out[wave] = GAMMA - s;
}

extern "C" void kernel_launch(void* const* d_in, const int* in_sizes, int n_in,
                              void* d_out, int out_size, void* d_ws, size_t ws_size,
                              hipStream_t stream) {
    const float* node_emb = (const float*)d_in[0];
    const float* rel_emb  = (const float*)d_in[1];
    const int*   triplets = (const int*)d_in[2];
    float*       out      = (float*)d_out;
    const int B = out_size;

    const size_t ws_needed = (size_t)2 * NCHUNK * REGION_HALVES * sizeof(unsigned short); // 516096
    if (ws_size < ws_needed) {
        const int grid = (B + 3) / 4;
        transe_direct<<<grid, 256, 0, stream>>>(node_emb, rel_emb, triplets, out, B);
        return;
    }

    unsigned short* tab16 = (unsigned short*)d_ws;

    const int conv_threads = 2 * NROWS * DIM / 8;   // 32000
    transe_convert<<<(conv_threads + 255) / 256, 256, 0, stream>>>(node_emb, rel_emb, tab16);

    const int grid = (B + TPB - 1) / TPB;           // 245 blocks, 1/CU
    transe_main<<<grid, THREADS, 0, stream>>>(tab16, triplets, node_emb, rel_emb, out, B);
}